// Round 1
// baseline (145.750 us; speedup 1.0000x reference)
//
#include <hip/hip_runtime.h>
#include <stdint.h>

// Problem constants (from reference)
#define B_SZ   512
#define T_SZ   100
#define NPRE   256
#define NPOST  256
#define KTOT   (B_SZ * T_SZ)   // 51200

typedef __bf16 bf16x8 __attribute__((ext_vector_type(8)));
typedef float  floatx4 __attribute__((ext_vector_type(4)));

__device__ __forceinline__ uint32_t bf16_rne(float v) {
    uint32_t bits = __float_as_uint(v);
    return (bits + 0x7FFFu + ((bits >> 16) & 1u)) >> 16;
}
__device__ __forceinline__ uint32_t pack_trunc2(float a, float b) {
    return (__float_as_uint(a) >> 16) | (__float_as_uint(b) & 0xFFFF0000u);
}

// ---------------------------------------------------------------------------
// R12: occupancy restructure. 512 blocks x 512 thr (8 waves), LDS unchanged
// at 64 KB -> still 2 blocks/CU but now 16 waves/CU = 4 waves/SIMD (was 2).
// __launch_bounds__(512,4) caps VGPR at 128; est. peak ~115 (pk50 + acc32 +
// x16 + addr) -> no spill expected.
//
// Old: 2 rounds x (scan 2 batches with 256 thr, then 2 phases).
// New: 1 round: ALL 4 batches scanned up front (thread = (grp = tid>>7) ->
// batch 4s+grp, p = tid&127; 100 serial steps/thread, half of before),
// then 4 phases g=0..3: group g deposits its pk into A_lds; every thread
// stages its q-column's K-chunk (kc = grp) of post into B_lds (two 16-wide
// load batches); sync; 4 kc x 8 MFMA per wave (wave w = p-group w, 16p x
// 128q slab, acc[8] = 32 VGPR); sync.
//
// Per-(b,p) scan fp32 sequence and RNE->bf16 packing bit-identical to R10;
// A/B LDS fragment layout, partial[bx] layout, and both reduce kernels
// unchanged.
// ---------------------------------------------------------------------------
__global__ __launch_bounds__(512, 4) void stdp_fused_gemm(
    const float* __restrict__ pre, const float* __restrict__ post,
    float* __restrict__ partial)
{
    __shared__ __align__(16) unsigned short A_lds[32][512];  // 32 KB
    __shared__ __align__(16) unsigned short B_lds[32][512];  // 32 KB

    const int bx   = blockIdx.x;      // 0..511
    const int s    = bx & 127;
    const int tile = bx >> 7;         // 0..3
    const int pt   = tile & 1;
    const int qt   = tile >> 1;
    const int tid  = threadIdx.x;     // 0..511
    const int lane = tid & 63, wave = tid >> 6;   // wave = p-group (0..7)
    const int l15 = lane & 15, l4 = lane >> 4;

    const int grp   = tid >> 7;       // 0..3 (wave-pair uniform): scan batch / B kc-chunk
    const int p_loc = tid & 127;      // scan row
    const int qloc  = tid & 127;      // B column
    const int qg = qloc >> 4, q15 = qloc & 15;
    const int pg = p_loc >> 4, lp = p_loc & 15;

    const float decay = 0.95122942450071400910f;   // expf(-1/20)

    // ---- scan: thread scans batch b = 4s+grp, row p (100 serial steps) ----
    uint32_t pk[50];
    {
        const int b = s * 4 + grp;
        const float* src = pre + (size_t)b * (T_SZ * NPRE) + pt * 128 + p_loc;
        float carry = 0.0f;
#pragma unroll
        for (int kc = 0; kc < 3; ++kc) {
            float x[32];
#pragma unroll
            for (int j = 0; j < 32; ++j)
                x[j] = src[(size_t)(kc * 32 + j) * NPRE];
#pragma unroll
            for (int j = 0; j < 16; ++j) {
                uint32_t lo = bf16_rne(carry);   // trace[t]=carry, then update
                carry = decay * (carry + x[2 * j]);
                uint32_t hi = bf16_rne(carry);
                carry = decay * (carry + x[2 * j + 1]);
                pk[kc * 16 + j] = lo | (hi << 16);
            }
        }
        float x[4];
#pragma unroll
        for (int j = 0; j < 4; ++j)
            x[j] = src[(size_t)(96 + j) * NPRE];
#pragma unroll
        for (int j = 0; j < 2; ++j) {
            uint32_t lo = bf16_rne(carry);
            carry = decay * (carry + x[2 * j]);
            uint32_t hi = bf16_rne(carry);
            carry = decay * (carry + x[2 * j + 1]);
            pk[48 + j] = lo | (hi << 16);
        }
    }

    floatx4 acc[8] = {};

#pragma unroll
    for (int g = 0; g < 4; ++g) {
        const int b = s * 4 + g;
        if (g) __syncthreads();   // previous phase's MFMA must finish before LDS reuse

        if (grp == g) {
            // deposit trace into A_lds fragment lines:
            // line kc*8+pg, slot w*16+lp holds t = kc*32 + w*8 .. +7
#pragma unroll
            for (int kc = 0; kc < 3; ++kc)
#pragma unroll
                for (int w = 0; w < 4; ++w)
                    *(uint4*)&A_lds[kc * 8 + pg][(w * 16 + lp) * 8] =
                        make_uint4(pk[kc * 16 + w * 4],     pk[kc * 16 + w * 4 + 1],
                                   pk[kc * 16 + w * 4 + 2], pk[kc * 16 + w * 4 + 3]);
            // kc = 3: t 96..99 real, 100..127 zero
            *(uint4*)&A_lds[24 + pg][lp * 8] = make_uint4(pk[48], pk[49], 0u, 0u);
#pragma unroll
            for (int w = 1; w < 4; ++w)
                *(uint4*)&A_lds[24 + pg][(w * 16 + lp) * 8] =
                    make_uint4(0u, 0u, 0u, 0u);
        }

        // ---- B staging: thread stages kc-chunk grp of column qloc ----
        // (two 16-wide load batches to stay under the 128-VGPR cap)
        const float* pb = post + (size_t)b * (T_SZ * NPOST) + qt * 128 + qloc;
        if (grp < 3) {
#pragma unroll
            for (int h = 0; h < 2; ++h) {
                float x[16];
#pragma unroll
                for (int j = 0; j < 16; ++j)
                    x[j] = pb[(size_t)(grp * 32 + h * 16 + j) * NPOST];
#pragma unroll
                for (int w2 = 0; w2 < 2; ++w2) {
                    const int w = h * 2 + w2;
                    *(uint4*)&B_lds[grp * 8 + qg][(w * 16 + q15) * 8] =
                        make_uint4(pack_trunc2(x[w2 * 8 + 0], x[w2 * 8 + 1]),
                                   pack_trunc2(x[w2 * 8 + 2], x[w2 * 8 + 3]),
                                   pack_trunc2(x[w2 * 8 + 4], x[w2 * 8 + 5]),
                                   pack_trunc2(x[w2 * 8 + 6], x[w2 * 8 + 7]));
                }
            }
        } else {
            // kc = 3: t 96..99 real + zeros
            float x[4];
#pragma unroll
            for (int j = 0; j < 4; ++j)
                x[j] = pb[(size_t)(96 + j) * NPOST];
            *(uint4*)&B_lds[24 + qg][q15 * 8] =
                make_uint4(pack_trunc2(x[0], x[1]), pack_trunc2(x[2], x[3]), 0u, 0u);
#pragma unroll
            for (int w = 1; w < 4; ++w)
                *(uint4*)&B_lds[24 + qg][(w * 16 + q15) * 8] =
                    make_uint4(0u, 0u, 0u, 0u);
        }
        __syncthreads();

        // ---- MFMA: 4 chunks of K=32; wave w covers 16p x 128q ----
#pragma unroll
        for (int kc = 0; kc < 4; ++kc) {
            bf16x8 a = *(const bf16x8*)&A_lds[kc * 8 + wave][lane * 8];
            bf16x8 bb[8];
#pragma unroll
            for (int gg = 0; gg < 8; ++gg)
                bb[gg] = *(const bf16x8*)&B_lds[kc * 8 + gg][lane * 8];
#pragma unroll
            for (int gg = 0; gg < 8; ++gg)
                acc[gg] = __builtin_amdgcn_mfma_f32_16x16x32_bf16(
                    a, bb[gg], acc[gg], 0, 0, 0);
        }
    }

    // ---- writeout: partial[bx][p_loc 128][q_loc 128]
    // C/D layout (m89/m91): col = lane&15, row = (lane>>4)*4 + reg
    float* pout = partial + (size_t)bx * (128 * 128);
    const int r0 = wave * 16 + l4 * 4;
#pragma unroll
    for (int gg = 0; gg < 8; ++gg) {
        const int c = gg * 16 + l15;
#pragma unroll
        for (int v = 0; v < 4; ++v)
            pout[(size_t)(r0 + v) * 128 + c] = acc[gg][v];
    }
}

// ---------------------------------------------------------------------------
// Reduce stage 1 (R10-proven): partial[bx = tile*128 + s][i], i = p*128+q.
// 2048 blocks x 256 thr; thread t: g = t>>16 (0..7), e = t&65535,
// tile = e>>14; sums s = g*16..+15 (4 indep chains).
// ---------------------------------------------------------------------------
__global__ __launch_bounds__(256) void stdp_reduce1(
    const float* __restrict__ partial, float* __restrict__ tmp)
{
    const int t = blockIdx.x * 256 + threadIdx.x;  // 0..524287
    const int g = t >> 16;                         // 0..7
    const int e = t & 65535;
    const int tile = e >> 14;
    const float* src = partial + ((size_t)(tile * 128 + g * 16) << 14) + (e & 16383);
    float a4[4] = {};
#pragma unroll
    for (int i = 0; i < 4; ++i)
#pragma unroll
        for (int u = 0; u < 4; ++u)
            a4[u] += src[(size_t)(u * 4 + i) << 14];
    tmp[t] = (a4[0] + a4[1]) + (a4[2] + a4[3]);
}

// ---------------------------------------------------------------------------
// Reduce stage 2 (R10-proven): 8 -> 1, un-tile, scale by (A+ - A-)/(B*T).
// ---------------------------------------------------------------------------
__global__ __launch_bounds__(256) void stdp_reduce2(
    const float* __restrict__ tmp, float* __restrict__ out)
{
    const int idx = blockIdx.x * 256 + threadIdx.x;  // 0..65535
    const int P = idx >> 8, Q = idx & 255;
    const int tile = (Q >> 7) * 2 + (P >> 7);
    const int e = (tile << 14) | ((P & 127) << 7) | (Q & 127);
    float a[4];
#pragma unroll
    for (int u = 0; u < 4; ++u)
        a[u] = tmp[(size_t)(2 * u) * 65536 + e] +
               tmp[(size_t)(2 * u + 1) * 65536 + e];
    const float scale = (0.005f - 0.00525f) * (1.0f / (float)KTOT);
    out[idx] = ((a[0] + a[1]) + (a[2] + a[3])) * scale;
}

// ---------------------------------------------------------------------------
extern "C" void kernel_launch(void* const* d_in, const int* in_sizes, int n_in,
                              void* d_out, int out_size, void* d_ws, size_t ws_size,
                              hipStream_t stream)
{
    const float* pre  = (const float*)d_in[0];   // [512,100,256]
    const float* post = (const float*)d_in[1];   // [512,100,256]
    float* out = (float*)d_out;                  // [256,256]

    // ws: partial 33.5 MB | tmp 2 MB
    float* partial = (float*)d_ws;
    float* tmp     = (float*)((char*)d_ws + (size_t)33554432);

    stdp_fused_gemm<<<512, 512, 0, stream>>>(pre, post, partial);
    stdp_reduce1<<<2048, 256, 0, stream>>>(partial, tmp);
    stdp_reduce2<<<256, 256, 0, stream>>>(tmp, out);
}

// Round 2
// 144.161 us; speedup vs baseline: 1.0110x; 1.0110x over previous
//
#include <hip/hip_runtime.h>
#include <stdint.h>

// Problem constants (from reference)
#define B_SZ   512
#define T_SZ   100
#define NPRE   256
#define NPOST  256
#define KTOT   (B_SZ * T_SZ)   // 51200

typedef __bf16 bf16x8 __attribute__((ext_vector_type(8)));
typedef float  floatx4 __attribute__((ext_vector_type(4)));

__device__ __forceinline__ uint32_t bf16_rne(float v) {
    uint32_t bits = __float_as_uint(v);
    return (bits + 0x7FFFu + ((bits >> 16) & 1u)) >> 16;
}
__device__ __forceinline__ uint32_t pack_trunc2(float a, float b) {
    return (__float_as_uint(a) >> 16) | (__float_as_uint(b) & 0xFFFF0000u);
}

// ---------------------------------------------------------------------------
// R13: deterministic in-block pipeline (T3+T14), allocator pinned.
// 256 blocks x 1024 thr (16 waves) = exactly 1 block/CU (LDS 128 KB), 4
// waves/SIMD; amdgpu_waves_per_eu(4,4) pins the VGPR budget to 128 so the
// allocator cannot sandbag to 64 and spill pk (R12 post-mortem).
//
// Block bx: s = bx&63 (batches 8s..8s+7), tile = bx>>6 (pt=tile&1 p-half,
// qt=tile>>1 q-half). All quadrant blocks of s are == s (mod 8) -> same XCD.
//
// Scan: each thread scans one (batch 8s+grp, p) column, grp = tid>>7 (R8's
// bit-exact fp32 scan + RNE->bf16 pack, pk[50]) — 8 batches in parallel.
//
// Phases g=0..7 over batches, A/B LDS double-buffered:
//   prologue: deposit A0 (grp0), stage B0 direct, barrier.
//   phase g: issue B loads for g+1 (16/thread, into regs)  <- T14 issue-early
//            MFMA on buf[g&1] (4 kc x 4 MFMA per wave, acc[4])
//            deposit A_{g+1} (grp g+1) + pack/write B_{g+1} -> buf[(g+1)&1]
//            barrier                                        <- one per phase
// Writes to buf[(g+1)&1] race only with phase g-1's reads of the same
// buffer, which the phase-g barrier already ordered.
//
// Wave w: p-group wpg=w>>1 (16 rows), q-half wqh=w&1 (64 cols); C/D layout
// (m89/m91) col=lane&15, row=(lane>>4)*4+reg.  partial[bx][128][128]
// (16.8 MB); reduce1 sums 64 s-blocks (same tmp layout), reduce2 unchanged.
// ---------------------------------------------------------------------------
__device__ __forceinline__ void deposit_A(unsigned short (*A)[512],
                                          const uint32_t* pk, int pg, int lp)
{
#pragma unroll
    for (int kc = 0; kc < 3; ++kc)
#pragma unroll
        for (int w = 0; w < 4; ++w)
            *(uint4*)&A[kc * 8 + pg][(w * 16 + lp) * 8] =
                make_uint4(pk[kc * 16 + w * 4],     pk[kc * 16 + w * 4 + 1],
                           pk[kc * 16 + w * 4 + 2], pk[kc * 16 + w * 4 + 3]);
    // kc = 3: t 96..99 real, 100..127 zero
    *(uint4*)&A[24 + pg][lp * 8] = make_uint4(pk[48], pk[49], 0u, 0u);
#pragma unroll
    for (int w = 1; w < 4; ++w)
        *(uint4*)&A[24 + pg][(w * 16 + lp) * 8] = make_uint4(0u, 0u, 0u, 0u);
}

// B staging split into issue-early LOAD and write-late STORE (T14).
// grp<6: t 16g..16g+15 (octs 2g,2g+1); grp6: t 96..99 (oct 12 + pad);
// grp7: pad octs 13..15 (zeros).
__device__ __forceinline__ void load_B(const float* pb, int grp, float* x)
{
    if (grp < 6) {
#pragma unroll
        for (int j = 0; j < 16; ++j)
            x[j] = pb[(size_t)(16 * grp + j) * NPOST];
    } else if (grp == 6) {
#pragma unroll
        for (int j = 0; j < 4; ++j)
            x[j] = pb[(size_t)(96 + j) * NPOST];
    }
}
__device__ __forceinline__ void store_B(unsigned short (*Bl)[512], int grp,
                                        int qg, int q15, const float* x)
{
    if (grp < 6) {
#pragma unroll
        for (int h = 0; h < 2; ++h) {
            const int o = 2 * grp + h;
            *(uint4*)&Bl[(o >> 2) * 8 + qg][((o & 3) * 16 + q15) * 8] =
                make_uint4(pack_trunc2(x[8 * h + 0], x[8 * h + 1]),
                           pack_trunc2(x[8 * h + 2], x[8 * h + 3]),
                           pack_trunc2(x[8 * h + 4], x[8 * h + 5]),
                           pack_trunc2(x[8 * h + 6], x[8 * h + 7]));
        }
    } else if (grp == 6) {
        *(uint4*)&Bl[24 + qg][q15 * 8] =
            make_uint4(pack_trunc2(x[0], x[1]), pack_trunc2(x[2], x[3]), 0u, 0u);
    } else {
#pragma unroll
        for (int o = 13; o < 16; ++o)
            *(uint4*)&Bl[24 + qg][((o & 3) * 16 + q15) * 8] =
                make_uint4(0u, 0u, 0u, 0u);
    }
}

__global__ __launch_bounds__(1024) __attribute__((amdgpu_waves_per_eu(4, 4)))
void stdp_fused_gemm(
    const float* __restrict__ pre, const float* __restrict__ post,
    float* __restrict__ partial)
{
    __shared__ __align__(16) unsigned short A_lds[2][32][512];  // 64 KB
    __shared__ __align__(16) unsigned short B_lds[2][32][512];  // 64 KB

    const int bx   = blockIdx.x;      // 0..255
    const int s    = bx & 63;
    const int tile = bx >> 6;         // 0..3
    const int pt   = tile & 1;
    const int qt   = tile >> 1;
    const int tid  = threadIdx.x;     // 0..1023
    const int lane = tid & 63, wave = tid >> 6;   // wave 0..15
    const int l15 = lane & 15, l4 = lane >> 4;

    const int grp   = tid >> 7;       // 0..7 (wave-pair uniform)
    const int p_loc = tid & 127;      // scan row
    const int qloc  = tid & 127;      // B column
    const int qg = qloc >> 4, q15 = qloc & 15;
    const int pg = p_loc >> 4, lp = p_loc & 15;
    const int wpg = wave >> 1;        // MFMA p-group (0..7)
    const int wqh = wave & 1;         // MFMA q-half (0..1)

    const float decay = 0.95122942450071400910f;   // expf(-1/20)
    const int b0 = s * 8;

    // ---- scan: thread scans batch b0+grp, row p (100 serial steps) ----
    uint32_t pk[50];
    {
        const int b = b0 + grp;
        const float* src = pre + (size_t)b * (T_SZ * NPRE) + pt * 128 + p_loc;
        float carry = 0.0f;
#pragma unroll
        for (int kc = 0; kc < 3; ++kc) {
            float x[32];
#pragma unroll
            for (int j = 0; j < 32; ++j)
                x[j] = src[(size_t)(kc * 32 + j) * NPRE];
#pragma unroll
            for (int j = 0; j < 16; ++j) {
                uint32_t lo = bf16_rne(carry);   // trace[t]=carry, then update
                carry = decay * (carry + x[2 * j]);
                uint32_t hi = bf16_rne(carry);
                carry = decay * (carry + x[2 * j + 1]);
                pk[kc * 16 + j] = lo | (hi << 16);
            }
        }
        float x[4];
#pragma unroll
        for (int j = 0; j < 4; ++j)
            x[j] = src[(size_t)(96 + j) * NPRE];
#pragma unroll
        for (int j = 0; j < 2; ++j) {
            uint32_t lo = bf16_rne(carry);
            carry = decay * (carry + x[2 * j]);
            uint32_t hi = bf16_rne(carry);
            carry = decay * (carry + x[2 * j + 1]);
            pk[48 + j] = lo | (hi << 16);
        }
    }

    floatx4 acc[4] = {};

    // ---- prologue: stage batch b0 into buffer 0 ----
    if (grp == 0) deposit_A(A_lds[0], pk, pg, lp);
    {
        float xb[16];
        load_B(post + (size_t)b0 * (T_SZ * NPOST) + qt * 128 + qloc, grp, xb);
        store_B(B_lds[0], grp, qg, q15, xb);
    }
    __syncthreads();

    // ---- 8 pipelined phases ----
#pragma unroll
    for (int g = 0; g < 8; ++g) {
        const int nb = g + 1;
        const int cb = g & 1;

        // T14 issue-early: next batch's B loads in flight across the MFMA
        float xn[16];
        if (nb < 8)
            load_B(post + (size_t)(b0 + nb) * (T_SZ * NPOST) + qt * 128 + qloc,
                   grp, xn);

        // MFMA on current buffer: wave tile 16p x 64q, 4 kc x 4 MFMA
#pragma unroll
        for (int kc = 0; kc < 4; ++kc) {
            bf16x8 a = *(const bf16x8*)&A_lds[cb][kc * 8 + wpg][lane * 8];
            bf16x8 bb[4];
#pragma unroll
            for (int gg = 0; gg < 4; ++gg)
                bb[gg] = *(const bf16x8*)&B_lds[cb][kc * 8 + wqh * 4 + gg][lane * 8];
#pragma unroll
            for (int gg = 0; gg < 4; ++gg)
                acc[gg] = __builtin_amdgcn_mfma_f32_16x16x32_bf16(
                    a, bb[gg], acc[gg], 0, 0, 0);
        }

        if (nb < 8) {
            // write-late into the other buffer (phase-g barrier already
            // ordered phase g-1's reads of it)
            if (grp == nb) deposit_A(A_lds[nb & 1], pk, pg, lp);
            store_B(B_lds[nb & 1], grp, qg, q15, xn);
            __syncthreads();
        }
    }

    // ---- writeout: partial[bx][p 128][q 128] ----
    float* pout = partial + (size_t)bx * (128 * 128);
    const int r0 = wpg * 16 + l4 * 4;
#pragma unroll
    for (int gg = 0; gg < 4; ++gg) {
        const int c = (wqh * 4 + gg) * 16 + l15;
#pragma unroll
        for (int v = 0; v < 4; ++v)
            pout[(size_t)(r0 + v) * 128 + c] = acc[gg][v];
    }
}

// ---------------------------------------------------------------------------
// Reduce stage 1: partial[bx = tile*64 + s][i], i = p*128+q.  2048 blocks x
// 256 thr; thread t: g = t>>16 (0..7), e = t&65535, tile = e>>14; sums
// s = g*8..+7 (4 indep chains).  tmp layout identical to R10's.
// ---------------------------------------------------------------------------
__global__ __launch_bounds__(256) void stdp_reduce1(
    const float* __restrict__ partial, float* __restrict__ tmp)
{
    const int t = blockIdx.x * 256 + threadIdx.x;  // 0..524287
    const int g = t >> 16;                         // 0..7
    const int e = t & 65535;
    const int tile = e >> 14;
    const float* src = partial + ((size_t)(tile * 64 + g * 8) << 14) + (e & 16383);
    float a4[4] = {};
#pragma unroll
    for (int i = 0; i < 2; ++i)
#pragma unroll
        for (int u = 0; u < 4; ++u)
            a4[u] += src[(size_t)(u * 2 + i) << 14];
    tmp[t] = (a4[0] + a4[1]) + (a4[2] + a4[3]);
}

// ---------------------------------------------------------------------------
// Reduce stage 2 (unchanged): 8 -> 1, un-tile, scale by (A+ - A-)/(B*T).
// ---------------------------------------------------------------------------
__global__ __launch_bounds__(256) void stdp_reduce2(
    const float* __restrict__ tmp, float* __restrict__ out)
{
    const int idx = blockIdx.x * 256 + threadIdx.x;  // 0..65535
    const int P = idx >> 8, Q = idx & 255;
    const int tile = (Q >> 7) * 2 + (P >> 7);
    const int e = (tile << 14) | ((P & 127) << 7) | (Q & 127);
    float a[4];
#pragma unroll
    for (int u = 0; u < 4; ++u)
        a[u] = tmp[(size_t)(2 * u) * 65536 + e] +
               tmp[(size_t)(2 * u + 1) * 65536 + e];
    const float scale = (0.005f - 0.00525f) * (1.0f / (float)KTOT);
    out[idx] = ((a[0] + a[1]) + (a[2] + a[3])) * scale;
}

// ---------------------------------------------------------------------------
extern "C" void kernel_launch(void* const* d_in, const int* in_sizes, int n_in,
                              void* d_out, int out_size, void* d_ws, size_t ws_size,
                              hipStream_t stream)
{
    const float* pre  = (const float*)d_in[0];   // [512,100,256]
    const float* post = (const float*)d_in[1];   // [512,100,256]
    float* out = (float*)d_out;                  // [256,256]

    // ws: partial 16.8 MB | tmp 2 MB
    float* partial = (float*)d_ws;
    float* tmp     = (float*)((char*)d_ws + (size_t)16777216);

    stdp_fused_gemm<<<256, 1024, 0, stream>>>(pre, post, partial);
    stdp_reduce1<<<2048, 256, 0, stream>>>(partial, tmp);
    stdp_reduce2<<<256, 256, 0, stream>>>(tmp, out);
}